// Round 6
// baseline (1018.621 us; speedup 1.0000x reference)
//
#include <hip/hip_runtime.h>
#include <hip/hip_bf16.h>

typedef short short8v __attribute__((ext_vector_type(8)));
typedef float float4v __attribute__((ext_vector_type(4)));

constexpr int Bb = 64;    // batch
constexpr int Cc = 32;    // capsules (softmax axis)
constexpr int Nn = 1152;  // routes
constexpr int Oo = 64;    // out channels
constexpr int Ii = 64;    // in channels
constexpr int NCH = 48;   // n-chunks (grid.x) -> 768 blocks = 3/CU
constexpr int CHN = 24;   // n per chunk
constexpr int OT  = 16;   // o-tiles (grid.y), 4 o per tile

__device__ __forceinline__ unsigned short bf16_rne(float f) {
    unsigned u = __float_as_uint(f);
    u += 0x7FFFu + ((u >> 16) & 1u);
    return (unsigned short)(u >> 16);
}
__device__ __forceinline__ float bf16_f(unsigned short h) {
    return __uint_as_float(((unsigned)h) << 16);
}
__device__ __forceinline__ float squash_elem(float s) {
    float sq = s * s;
    return (sq / (1.f + sq)) * s / sqrtf(sq + 1e-8f);
}

// split 8 f32 into hi (RNE) / lo (truncated) bf16 fragments, in-register
__device__ __forceinline__ void split8(const float4& f0, const float4& f1,
                                       short8v& h, short8v& lo) {
    float a[8] = {f0.x, f0.y, f0.z, f0.w, f1.x, f1.y, f1.z, f1.w};
#pragma unroll
    for (int e = 0; e < 8; ++e) {
        unsigned b = __float_as_uint(a[e]);
        unsigned r = b + 0x7FFFu + ((b >> 16) & 1u);   // RNE hi
        h[e] = (short)(r >> 16);
        float res = a[e] - __uint_as_float(r & 0xFFFF0000u);
        lo[e] = (short)(__float_as_uint(res) >> 16);   // truncated lo
    }
}

// ---- pre-split x into hi/lo bf16 planes (one-time, ~38 MB traffic) ---------
__global__ __launch_bounds__(256) void prep_x(const float* __restrict__ x,
                                              unsigned short* __restrict__ xh,
                                              unsigned short* __restrict__ xl) {
    size_t g = (size_t)blockIdx.x * 256 + threadIdx.x;  // one float4 per thread
    float4 v = ((const float4*)x)[g];
    float a[4] = {v.x, v.y, v.z, v.w};
    ushort4 H, L;
    unsigned short* hp = (unsigned short*)&H;
    unsigned short* lp = (unsigned short*)&L;
#pragma unroll
    for (int e = 0; e < 4; ++e) {
        unsigned short hb = bf16_rne(a[e]);
        hp[e] = hb;
        lp[e] = bf16_rne(a[e] - bf16_f(hb));
    }
    ((ushort4*)xh)[g] = H;
    ((ushort4*)xl)[g] = L;
}

// ---- fused pass: B-frags DIRECT from global w (no LDS, no syncthreads) -----
// MODE 0: acc += u (iter-0 uniform weights; /32 applied in reduce)
// MODE 1: acc += softmax_c(u*V) * u
// Block (n-chunk, o-quad): 64 b x 32 c x 4 o. All 4 waves read the same w
// fragments (L2 absorbs 4x; bare s_barrier keeps waves lockstep for reuse).
template <int MODE>
__global__ __launch_bounds__(256, 3) void caps_pass(
    const float* __restrict__ w, const unsigned short* __restrict__ xh,
    const unsigned short* __restrict__ xl, const float* __restrict__ V,
    float* __restrict__ part) {
    const int t = threadIdx.x;
    const int l = t & 63, wv = t >> 6;
    const int ch = blockIdx.x, ot = blockIdx.y;
    const int obase = ot * 4;
    const int kg = l >> 4, lm = l & 15;
    const int cc0 = lm >> 2, ol = lm & 3;
    const int n0 = ch * CHN;

    // per-lane V: b = 16wv+4kg+r, c = 4t8+cc0, o = obase+ol
    float Vreg[8][4];
    if constexpr (MODE == 1) {
#pragma unroll
        for (int t8 = 0; t8 < 8; ++t8) {
            int c = 4 * t8 + cc0;
#pragma unroll
            for (int r = 0; r < 4; ++r) {
                int b = 16 * wv + 4 * kg + r;
                Vreg[t8][r] = V[((size_t)b * Cc + c) * Oo + obase + ol];
            }
        }
    }
    float4v acc4[8];   // MODE 0 accumulators (chained through MFMA C)
    float accs[8][4];  // MODE 1 accumulators
#pragma unroll
    for (int t8 = 0; t8 < 8; ++t8) {
        acc4[t8] = (float4v){0.f, 0.f, 0.f, 0.f};
#pragma unroll
        for (int r = 0; r < 4; ++r) accs[t8][r] = 0.f;
    }

    // n-invariant address parts
    const size_t wlane = ((size_t)cc0 * Nn * Oo + obase + ol) * Ii + kg * 8;
    const size_t xlane = (size_t)(16 * wv + lm) * Nn * Ii + kg * 8;
    constexpr size_t T8STRIDE = (size_t)4 * Nn * Oo * Ii;  // c += 4 per t8

    for (int j = 0; j < CHN; ++j) {
        const int n = n0 + j;
        const float* wn = w + wlane + (size_t)n * (Oo * Ii);
        const unsigned short* xhn = xh + xlane + (size_t)n * Ii;
        const unsigned short* xln = xl + xlane + (size_t)n * Ii;

        // A-frags: row b = 16wv+lm, k = kg*8 (+32)
        short8v ah0 = *(const short8v*)xhn;
        short8v al0 = *(const short8v*)xln;
        short8v ah1 = *(const short8v*)(xhn + 32);
        short8v al1 = *(const short8v*)(xln + 32);

        float u[8][4];
#pragma unroll
        for (int t8 = 0; t8 < 8; ++t8) {
            const float* wp = wn + (size_t)t8 * T8STRIDE;
            float4 f0 = *(const float4*)(wp);
            float4 f1 = *(const float4*)(wp + 4);
            float4 f2 = *(const float4*)(wp + 32);
            float4 f3 = *(const float4*)(wp + 36);
            short8v bh0, bl0, bh1, bl1;
            split8(f0, f1, bh0, bl0);
            split8(f2, f3, bh1, bl1);
            float4v a;
            if constexpr (MODE == 0) a = acc4[t8];
            else a = (float4v){0.f, 0.f, 0.f, 0.f};
            a = __builtin_amdgcn_mfma_f32_16x16x32_bf16(ah0, bh0, a, 0, 0, 0);
            a = __builtin_amdgcn_mfma_f32_16x16x32_bf16(al0, bh0, a, 0, 0, 0);
            a = __builtin_amdgcn_mfma_f32_16x16x32_bf16(ah0, bl0, a, 0, 0, 0);
            a = __builtin_amdgcn_mfma_f32_16x16x32_bf16(ah1, bh1, a, 0, 0, 0);
            a = __builtin_amdgcn_mfma_f32_16x16x32_bf16(al1, bh1, a, 0, 0, 0);
            a = __builtin_amdgcn_mfma_f32_16x16x32_bf16(ah1, bl1, a, 0, 0, 0);
            if constexpr (MODE == 0) {
                acc4[t8] = a;
            } else {
                u[t8][0] = a[0]; u[t8][1] = a[1];
                u[t8][2] = a[2]; u[t8][3] = a[3];
            }
        }

        if constexpr (MODE == 1) {
            // softmax over 32 c = 8 in-lane (t8) x 4 lanes (xor 4, 8)
#pragma unroll
            for (int r = 0; r < 4; ++r) {
                float m = -1e30f;
#pragma unroll
                for (int t8 = 0; t8 < 8; ++t8)
                    m = fmaxf(m, u[t8][r] * Vreg[t8][r]);
                m = fmaxf(m, __shfl_xor(m, 4));
                m = fmaxf(m, __shfl_xor(m, 8));
                float Z = 0.f;
#pragma unroll
                for (int t8 = 0; t8 < 8; ++t8) {
                    float e = __expf(u[t8][r] * Vreg[t8][r] - m);
                    Z += e;
                    u[t8][r] *= e;  // u now holds e*u
                }
                Z += __shfl_xor(Z, 4);
                Z += __shfl_xor(Z, 8);
                float rz = 1.f / Z;
#pragma unroll
                for (int t8 = 0; t8 < 8; ++t8) accs[t8][r] += u[t8][r] * rz;
            }
        }

        // bare barrier (no waitcnt drain): keep waves lockstep so the 4x
        // duplicated w reads stay L2-resident.
        __builtin_amdgcn_s_barrier();
    }

    // write per-chunk partials: part[ch][b][c][o]
#pragma unroll
    for (int t8 = 0; t8 < 8; ++t8)
#pragma unroll
        for (int r = 0; r < 4; ++r) {
            int b = 16 * wv + 4 * kg + r;
            int c = 4 * t8 + cc0;
            int o = obase + ol;
            float val = (MODE == 0) ? acc4[t8][r] : accs[t8][r];
            part[(((size_t)ch * Bb + b) * Cc + c) * Oo + o] = val;
        }
}

// ---- reduce partials over chunks; squash; update V / write out -------------
__global__ void reduce_caps(const float* __restrict__ part,
                            float* __restrict__ V, float* __restrict__ out,
                            int mode) {
    int bc = blockIdx.x;       // b*32+c, 2048 blocks
    int o = threadIdx.x;       // 64
    size_t base = (size_t)bc * 64 + o;
    float s = 0.f;
    for (int c = 0; c < NCH; ++c) s += part[(size_t)c * (Bb * Cc * Oo) + base];
    if (mode == 0)      V[base] = squash_elem(s * (1.f / 32.f));
    else if (mode == 1) V[base] += squash_elem(s);
    else                out[base] = squash_elem(s);
}

extern "C" void kernel_launch(void* const* d_in, const int* in_sizes, int n_in,
                              void* d_out, int out_size, void* d_ws, size_t ws_size,
                              hipStream_t stream) {
    const float* x = (const float*)d_in[0];          // [64,1152,64]
    const float* w = (const float*)d_in[1];          // [32,1152,64,64]
    float* out = (float*)d_out;                      // [64,32,64]

    const size_t XE = (size_t)Bb * Nn * Ii;          // 4,718,592
    unsigned short* xh = (unsigned short*)d_ws;
    unsigned short* xl = xh + XE;
    float* part = (float*)(xl + XE);                 // 48*64*32*64 f32 ~ 25 MB
    float* V = part + (size_t)NCH * Bb * Cc * Oo;

    prep_x<<<(int)(XE / 4 / 256), 256, 0, stream>>>(x, xh, xl);

    caps_pass<0><<<dim3(NCH, OT), 256, 0, stream>>>(w, xh, xl, nullptr, part);
    reduce_caps<<<Bb * Cc, 64, 0, stream>>>(part, V, out, 0);   // V = v0
    caps_pass<1><<<dim3(NCH, OT), 256, 0, stream>>>(w, xh, xl, V, part);
    reduce_caps<<<Bb * Cc, 64, 0, stream>>>(part, V, out, 1);   // V += v1
    caps_pass<1><<<dim3(NCH, OT), 256, 0, stream>>>(w, xh, xl, V, part);
    reduce_caps<<<Bb * Cc, 64, 0, stream>>>(part, V, out, 2);   // out = v2
}